// Round 14
// baseline (193.308 us; speedup 1.0000x reference)
//
#include <hip/hip_runtime.h>
#include <hip/hip_bf16.h>

#define DEVI __device__ __forceinline__

typedef __attribute__((ext_vector_type(8))) short short8;
typedef __attribute__((ext_vector_type(4))) short short4v;
typedef __attribute__((ext_vector_type(4))) float floatx4;

static constexpr int B_ = 2, T_ = 2048, C_ = 1024, H_ = 16, D_ = 64;
static constexpr float LOG2E = 1.44269504088896f;

DEVI float bf2f(unsigned short u) {
    union { unsigned int i; float f; } v; v.i = ((unsigned int)u) << 16; return v.f;
}
DEVI unsigned short f2bf(float f) {
    union { float f; unsigned int i; } v; v.f = f;
    unsigned int x = v.i;
    return (unsigned short)((x + 0x7fffu + ((x >> 16) & 1u)) >> 16);
}
DEVI unsigned int pk2bf(float lo, float hi) {
#if __has_builtin(__builtin_amdgcn_cvt_pk_bf16_f32)
    typedef __attribute__((ext_vector_type(2))) __bf16 bf16x2;
    union { bf16x2 v; unsigned int u; } r;
    r.v = __builtin_amdgcn_cvt_pk_bf16_f32(lo, hi);
    return r.u;
#else
    return (unsigned int)f2bf(lo) | ((unsigned int)f2bf(hi) << 16);
#endif
}
DEVI float fast_exp2(float x) {
#if __has_builtin(__builtin_amdgcn_exp2f)
    return __builtin_amdgcn_exp2f(x);
#else
    return __expf(x * 0.6931471805599453f);
#endif
}

// async global->LDS, 16B per lane. LDS dest must be wave_base + lane*16.
DEVI void async16(const unsigned short* g, unsigned short* l) {
    __builtin_amdgcn_global_load_lds((const __attribute__((address_space(1))) void*)g,
                                     (__attribute__((address_space(3))) void*)l, 16, 0, 0);
}

// ================= shared prep bodies =================
DEVI void tr_body(const float* in, unsigned short* out, int K, int N, int bx, int by,
                  int tid, float (*tile)[65], float scale, bool skiphi) {
    int k0 = by * 64, n0 = bx * 64;
#pragma unroll
    for (int r = 0; r < 4; r++) {
        int ci = tid + r * 256;
        int row = ci >> 4, c4 = (ci & 15) * 4;
        float4 v = *(const float4*)&in[(size_t)(k0 + row) * N + n0 + c4];
        tile[row][c4 + 0] = v.x; tile[row][c4 + 1] = v.y;
        tile[row][c4 + 2] = v.z; tile[row][c4 + 3] = v.w;
    }
    __syncthreads();
#pragma unroll
    for (int r = 0; r < 2; r++) {
        int ci = tid + r * 256;
        int row = ci >> 3, c8 = (ci & 7) * 8;
        if (skiphi && row >= 56) continue;   // aug blocks own these output rows
        union { unsigned short u[8]; short8 s; } o;
#pragma unroll
        for (int j = 0; j < 8; j++) o.u[j] = f2bf(tile[c8 + j][row] * scale);
        *(short8*)&out[(size_t)(n0 + row) * K + k0 + c8] = o.s;
    }
}

DEVI void bias_body(const float* d_bias, const float* w_disc, float* bias,
                    int h, int tid, float* red) {
    float s = 0.f;
    for (int t = tid; t < T_; t += 256) s += d_bias[h * T_ + t];
    red[tid] = s;
    __syncthreads();
    for (int st = 128; st > 0; st >>= 1) {
        if (tid < st) red[tid] += red[tid + st];
        __syncthreads();
    }
    float mean = red[0] * (1.0f / T_);
    float wd = w_disc[h] * LOG2E;
    for (int t = tid; t < T_; t += 256) bias[h * T_ + t] = (d_bias[h * T_ + t] - mean) * wd;
}

// ================= prep: x->bf16, W_attn^T (scaled/augmented) =================
// q_eff/k_eff are LINEAR in x, so the augmentation folds into the weights:
//   Wq_eff = [qscale*ws*Wq[:, :56], qscale*wr*(Wk@W_recip)]   (plain qscale*ws*Wq if !ra)
//   Wk_eff = [ws*Wk[:, :56],        wr*(Wq@W_recip)]          (plain ws*Wk if !ra)
// tr blocks skip q/k rows d>=56; aug blocks (32) write exactly those rows -> no race.
// wp_t + bias blocks live in the k_gemm_qkv launch (fill its idle CU slots).
__global__ __launch_bounds__(256) void k_prep(const float* __restrict__ x,
                                              const float* __restrict__ W_attn,
                                              const float* __restrict__ W_recip,
                                              const float* __restrict__ w_std,
                                              const float* __restrict__ w_rec,
                                              unsigned short* __restrict__ x_bf,
                                              unsigned short* __restrict__ wa_t) {
    __shared__ float tile[64][65];
    int bid = blockIdx.x, tid = threadIdx.x;
    if (bid < 2048) {
        int i = bid * 256 + tid;
        const float4* p = (const float4*)x + (size_t)i * 2;
        float4 a = p[0], b = p[1];
        union { unsigned short u[8]; short8 s; } r;
        r.u[0] = f2bf(a.x); r.u[1] = f2bf(a.y); r.u[2] = f2bf(a.z); r.u[3] = f2bf(a.w);
        r.u[4] = f2bf(b.x); r.u[5] = f2bf(b.y); r.u[6] = f2bf(b.z); r.u[7] = f2bf(b.w);
        *(short8*)&x_bf[(size_t)i * 8] = r.s;
    } else if (bid < 2816) {
        int idx = bid - 2048;
        int bx = idx % 48, by = idx / 48;
        int sec = bx >> 4, h = bx & 15;
        float ws = sqrtf(fmaxf(w_std[h], 1e-8f));
        float sc = (sec == 0) ? ws * (0.125f * LOG2E) : (sec == 1 ? ws : 1.0f);
        tr_body(W_attn, wa_t, 1024, 3072, bx, by, tid, tile, sc, sec < 2);
    } else {
        // augmented weight rows: for (h, side) write wa_t rows side*1024 + h*64 + 56..63
        int idx = bid - 2816;           // 0..31
        int h = idx & 15, side = idx >> 4;   // side 0: q_eff rows, 1: k_eff rows
        float* WrS = &tile[0][0];
        for (int i = tid; i < 512; i += 256) WrS[i] = W_recip[i];
        __syncthreads();
        float wrv = sqrtf(fmaxf(w_rec[h], 1e-8f));
        float wsv = sqrtf(fmaxf(w_std[h], 1e-8f));
        bool ra = w_rec[h] > 0.1f;
        float sc = (side == 0 ? 0.125f * LOG2E : 1.0f) * (ra ? wrv : wsv);
        int dst0 = side * 1024 + h * 64 + 56;
        for (int kk = tid; kk < 1024; kk += 256) {
            const float* srow = W_attn + (size_t)kk * 3072;
            float out[8];
            if (ra) {
                // q_aug <- Wk@Wr, k_aug <- Wq@Wr (other side's columns)
                int sc0 = (1 - side) * 1024 + h * 64;
#pragma unroll
                for (int r = 0; r < 8; r++) out[r] = 0.f;
                for (int dd = 0; dd < 64; dd++) {
                    float v = srow[sc0 + dd];
#pragma unroll
                    for (int r = 0; r < 8; r++) out[r] += v * WrS[dd * 8 + r];
                }
            } else {
                int sc0 = side * 1024 + h * 64 + 56;   // plain same-side columns
#pragma unroll
                for (int r = 0; r < 8; r++) out[r] = srow[sc0 + r];
            }
#pragma unroll
            for (int r = 0; r < 8; r++)
                wa_t[(size_t)(dst0 + r) * 1024 + kk] = f2bf(sc * out[r]);
        }
    }
}

// ========== bf16 GEMM 128x128 -> fragment-linear qe/ke/vt (+ folded wp_t/bias) ==========
// R12: BK=64 dual 32-wide buffers (32 MFMAs per barrier pair); epilogue staging unions
// with k-loop buffers (LDS 32KB -> 4 blocks/CU). R10: XCD-locality 2D chunk.
// R13: 1D grid 1040 — blocks 0..767 GEMM, 768..1023 wp_t transpose, 1024..1039 bias.
__global__ __launch_bounds__(256) void k_gemm_qkv(const unsigned short* __restrict__ A,
                                                  const unsigned short* __restrict__ Bt,
                                                  const float* __restrict__ W_proj,
                                                  const float* __restrict__ d_bias,
                                                  const float* __restrict__ w_disc,
                                                  unsigned short* __restrict__ qe,
                                                  unsigned short* __restrict__ ke,
                                                  unsigned short* __restrict__ vt,
                                                  unsigned short* __restrict__ wp_t,
                                                  float* __restrict__ bias,
                                                  int M, int N, int K) {
    union SM {
        unsigned short buf[4][128 * 32];    // A0,A1,B0,B1 (k-loop)        32 KB
        unsigned short stg[4][4096];        // per-wave staging (epilogue) 32 KB
        struct { float tile[64][65]; float red[256]; } p;   // prep blocks ~17.7 KB
    };
    __shared__ __align__(16) SM sm;
    int bid = blockIdx.x, tid = threadIdx.x;
    if (bid >= 768) {
        if (bid < 1024) {
            int idx = bid - 768;
            tr_body(W_proj, wp_t, 1024, 1024, idx & 15, idx >> 4, tid, sm.p.tile, 1.0f, false);
        } else {
            bias_body(d_bias, w_disc, bias, bid - 1024, tid, sm.p.red);
        }
        return;
    }
    int b1d = bid;                              // HW linear id
    int xcd = b1d & 7, i6 = b1d >> 3;           // i6: 0..95
    int bx = (xcd & 1) * 12 + i6 % 12;          // 2 bx-groups x 4 by-groups = 8 XCD tiles
    int by = (xcd >> 1) * 8 + i6 / 12;
    int m0 = by * 128, n0 = bx * 128;
    int l = tid & 63, w = tid >> 6;
    int wm = (w >> 1) * 64, wn = (w & 1) * 64;
    int lm = l & 15, lq = l >> 4;
    floatx4 acc[4][4];
#pragma unroll
    for (int a = 0; a < 4; a++)
#pragma unroll
        for (int b = 0; b < 4; b++) acc[a][b] = {0.f, 0.f, 0.f, 0.f};

    for (int k0 = 0; k0 < K; k0 += 64) {
        __syncthreads();
#pragma unroll
        for (int r = 0; r < 2; r++) {
            int ci = tid + r * 256;
            int row = ci >> 2, off = (ci & 3) * 8;
            async16(&A[(size_t)(m0 + row) * K + k0 + off],       &sm.buf[0][row * 32 + off]);
            async16(&A[(size_t)(m0 + row) * K + k0 + 32 + off],  &sm.buf[1][row * 32 + off]);
            async16(&Bt[(size_t)(n0 + row) * K + k0 + off],      &sm.buf[2][row * 32 + off]);
            async16(&Bt[(size_t)(n0 + row) * K + k0 + 32 + off], &sm.buf[3][row * 32 + off]);
        }
        __syncthreads();
#pragma unroll
        for (int half = 0; half < 2; half++) {
            const unsigned short* Ah = sm.buf[half];
            const unsigned short* Bh = sm.buf[2 + half];
            short8 af[4], bf[4];
#pragma unroll
            for (int t = 0; t < 4; t++) af[t] = *(short8*)&Ah[(wm + t * 16 + lm) * 32 + lq * 8];
#pragma unroll
            for (int t = 0; t < 4; t++) bf[t] = *(short8*)&Bh[(wn + t * 16 + lm) * 32 + lq * 8];
#pragma unroll
            for (int tm = 0; tm < 4; tm++)
#pragma unroll
                for (int tn = 0; tn < 4; tn++)
                    acc[tm][tn] = __builtin_amdgcn_mfma_f32_16x16x32_bf16(af[tm], bf[tn], acc[tm][tn], 0, 0, 0);
        }
    }
    __syncthreads();    // all waves done reading buf before stg overwrites it
    // ---- epilogue: stage fragment-linear tile in LDS, then coalesced copy-out ----
    int sec = bx >> 3;                      // 0=q_eff, 1=k_eff, 2=v  (block-uniform)
    int b = by >> 4;                        // batch
    int head = ((n0 & 1023) >> 6) + (wn >> 6);
    size_t bhbase = (size_t)(b * 16 + head) * 131072;
    int tloc0 = (m0 & 2047) + wm;           // wave's first t within batch (multiple of 64)
    unsigned short* dst = (sec == 0) ? qe : (sec == 1) ? ke : vt;
    unsigned short* S = sm.stg[w];
    if (sec < 2) {
        // qe/ke elem(t,d): (t>>4)*1024 + (t&15)*8 + (d>>5)*512 + ((d>>3)&3)*128 + (d&7)
#pragma unroll
        for (int tm = 0; tm < 4; tm++)
#pragma unroll
            for (int tn = 0; tn < 4; tn++) {
                int base = tm * 1024 + (tn >> 1) * 512 + ((tn & 1) * 2 + (lm >> 3)) * 128 +
                           (lm & 7) + lq * 32;           // + r*8 per element
#pragma unroll
                for (int r = 0; r < 4; r++) S[base + r * 8] = f2bf(acc[tm][tn][r]);
            }
    } else {
        // vt elem(t,d): (t>>5)*2048 + (d>>4)*512 + ((t>>3)&3)*128 + (d&15)*8 + (t&7)
#pragma unroll
        for (int tm = 0; tm < 4; tm++)
#pragma unroll
            for (int tn = 0; tn < 4; tn++) {
                int base = (tm >> 1) * 2048 + tn * 512 + ((tm & 1) * 2 + (lq >> 1)) * 128 +
                           lm * 8 + (lq & 1) * 4;        // r contiguous
                union { unsigned short u[4]; short4v s4; } o;
#pragma unroll
                for (int r = 0; r < 4; r++) o.u[r] = f2bf(acc[tm][tn][r]);
                *(short4v*)&S[base] = o.s4;
            }
    }
    // same-wave LDS RAW: compiler inserts the lgkmcnt wait; no cross-wave sharing.
    size_t gbase = bhbase + ((sec < 2) ? (size_t)(tloc0 >> 4) * 1024
                                       : (size_t)(tloc0 >> 5) * 2048);
#pragma unroll
    for (int i = 0; i < 8; i++) {
        short8 v = *(const short8*)&S[(size_t)(i * 64 + l) * 8];
        *(short8*)&dst[gbase + (size_t)(i * 64 + l) * 8] = v;
    }
}

// ================= bf16 GEMM 128x64 (fp32 out) — for the proj GEMM =================
// NOTE (R4): keep 128x64 / 512-block shape for N=1024 (2 blocks/CU).
// R14: reverted to R12's BK=64 dual buffers (R13's BK=128 suspected -3us: 4-deep load
// bursts at only 2 blocks/CU; single-variable test vs the R13 bundle).
// R10: XCD-locality 8x8 chunk.
__global__ __launch_bounds__(256) void k_gemm64(const unsigned short* __restrict__ A,
                                                const unsigned short* __restrict__ Bt,
                                                float* __restrict__ C, int M, int N, int K) {
    __shared__ __align__(16) unsigned short As[2][128 * 32];
    __shared__ __align__(16) unsigned short Bs[2][64 * 32];
    int b1d = blockIdx.y * 16 + blockIdx.x;     // HW linear id (x fastest)
    int xcd = b1d & 7, i6 = b1d >> 3;           // i6: 0..63
    int bx = (xcd & 1) * 8 + (i6 & 7);          // 2 bx-groups x 4 by-groups = 8 XCD tiles
    int by = (xcd >> 1) * 8 + (i6 >> 3);
    int m0 = by * 128, n0 = bx * 64;
    int tid = threadIdx.x, l = tid & 63, w = tid >> 6;
    int wm = w * 32;
    int lm = l & 15, lq = l >> 4;
    floatx4 acc[2][4];
#pragma unroll
    for (int a = 0; a < 2; a++)
#pragma unroll
        for (int b = 0; b < 4; b++) acc[a][b] = {0.f, 0.f, 0.f, 0.f};

    for (int k0 = 0; k0 < K; k0 += 64) {
        __syncthreads();
#pragma unroll
        for (int r = 0; r < 2; r++) {
            int ci = tid + r * 256;
            int row = ci >> 2, off = (ci & 3) * 8;
            async16(&A[(size_t)(m0 + row) * K + k0 + off],      &As[0][row * 32 + off]);
            async16(&A[(size_t)(m0 + row) * K + k0 + 32 + off], &As[1][row * 32 + off]);
        }
        {
            int row = tid >> 2, off = (tid & 3) * 8;
            async16(&Bt[(size_t)(n0 + row) * K + k0 + off],      &Bs[0][row * 32 + off]);
            async16(&Bt[(size_t)(n0 + row) * K + k0 + 32 + off], &Bs[1][row * 32 + off]);
        }
        __syncthreads();
#pragma unroll
        for (int half = 0; half < 2; half++) {
            short8 af[2], bf[4];
#pragma unroll
            for (int t = 0; t < 2; t++) af[t] = *(short8*)&As[half][(wm + t * 16 + lm) * 32 + lq * 8];
#pragma unroll
            for (int t = 0; t < 4; t++) bf[t] = *(short8*)&Bs[half][(t * 16 + lm) * 32 + lq * 8];
#pragma unroll
            for (int tm = 0; tm < 2; tm++)
#pragma unroll
                for (int tn = 0; tn < 4; tn++)
                    acc[tm][tn] = __builtin_amdgcn_mfma_f32_16x16x32_bf16(af[tm], bf[tn], acc[tm][tn], 0, 0, 0);
        }
    }
#pragma unroll
    for (int tm = 0; tm < 2; tm++)
#pragma unroll
        for (int tn = 0; tn < 4; tn++) {
            int row = m0 + wm + tm * 16 + lq * 4;
            int col = n0 + tn * 16 + lm;
#pragma unroll
            for (int r = 0; r < 4; r++) C[(size_t)(row + r) * N + col] = acc[tm][tn][r];
        }
}

// ================= attention helpers =================
// Max-free softmax: scores in log2 domain are tiny (|s| < ~10 << 128), so
// exp2 cannot overflow and the running max / alpha rescale is unnecessary.
// l is a per-lane partial, reduced once in the epilogue.
DEVI void exp_pack(float sv[4][4], float& l_part, unsigned int pk[4][2]) {
#pragma unroll
    for (int js = 0; js < 4; js++)
#pragma unroll
        for (int r = 0; r < 4; r++) {
            float p = fast_exp2(sv[js][r]);
            sv[js][r] = p;
            l_part += p;
        }
#pragma unroll
    for (int js = 0; js < 4; js++) {
        pk[js][0] = pk2bf(sv[js][0], sv[js][1]);
        pk[js][1] = pk2bf(sv[js][2], sv[js][3]);
    }
}

DEVI short8 make_pf(const unsigned int pk[4][2], int c, int srcLo, int srcHi, bool hi) {
    int a0 = __shfl((int)pk[2 * c][0], srcLo);
    int a1 = __shfl((int)pk[2 * c][1], srcLo);
    int a2 = __shfl((int)pk[2 * c][0], srcHi);
    int a3 = __shfl((int)pk[2 * c][1], srcHi);
    int b0 = __shfl((int)pk[2 * c + 1][0], srcLo);
    int b1 = __shfl((int)pk[2 * c + 1][1], srcLo);
    int b2 = __shfl((int)pk[2 * c + 1][0], srcHi);
    int b3 = __shfl((int)pk[2 * c + 1][1], srcHi);
    union { int i[4]; short8 s; } pf;
    pf.i[0] = hi ? b0 : a0;
    pf.i[1] = hi ? b1 : a1;
    pf.i[2] = hi ? b2 : a2;
    pf.i[3] = hi ? b3 : a3;
    return pf.s;
}

struct KF { short8 lo[4]; short8 hi[4]; };

// ================= flash attention: paired tiles + phase-split + XCD swizzle ===========
// R9: XCD swizzle -> K/V L2-resident (FETCH 63.5->12.5MB). R11: phase-split in the
// latency-bound regime -> 50.4->49.2us. Near the structural floor for this decomposition.
__global__ __launch_bounds__(256) void k_attn(const unsigned short* __restrict__ qe,
                                              const unsigned short* __restrict__ ke,
                                              const unsigned short* __restrict__ vt,
                                              const float* __restrict__ bias,
                                              unsigned short* __restrict__ obf) {
    __shared__ __align__(16) float psum[2][64][36];   // [pairL][lane][OA16|OB16|lA|lB]
    int b1d = blockIdx.y * 32 + blockIdx.x;     // HW linear id (x fastest)
    int xcd = b1d & 7, j = b1d >> 3;            // j: 0..127
    int bh = xcd * 4 + (j >> 5);                // 4 bh per XCD (L2-resident K/V)
    int pxq = j & 31;                           // pair-quad within bh: 0..31
    int b = bh >> 4, h = bh & 15;
    int tid = threadIdx.x, l = tid & 63, w = tid >> 6;
    int pairL = w >> 1;                         // local pair: 0/1
    int phase = w & 1;                          // 0: even steps, 1: odd steps
    int lm = l & 15, lq = l >> 4;
    int l8 = l * 8;
    const size_t hb = (size_t)bh * 131072;
    const unsigned short* qeh = qe + hb;
    const unsigned short* keh = ke + hb;
    const unsigned short* vth = vt + hb;
    const float* biash = bias + h * T_;

    int gA = pxq * 2 + pairL;               // 0..63 (light tile)
    int gB = 127 - gA;                      // 64..127 (heavy tile)
    int itA = (gA >> 2) + 1, itB = (gB >> 2) + 1;
    int irowA = gA * 16 + lm, irowB = gB * 16 + lm;

    short8 qA0 = *(const short8*)(qeh + (size_t)gA * 1024 + l8);
    short8 qA1 = *(const short8*)(qeh + (size_t)gA * 1024 + 512 + l8);
    short8 qB0 = *(const short8*)(qeh + (size_t)gB * 1024 + l8);
    short8 qB1 = *(const short8*)(qeh + (size_t)gB * 1024 + 512 + l8);

    floatx4 OA[4], OB[4];
#pragma unroll
    for (int i = 0; i < 4; i++) { OA[i] = {0.f, 0.f, 0.f, 0.f}; OB[i] = {0.f, 0.f, 0.f, 0.f}; }
    float lA = 0.f, lB = 0.f;               // per-lane partial denominators

    const int srcLo = ((lq & 1) * 2) * 16 + lm;
    const int srcHi = srcLo + 16;
    const bool hi = (lq >> 1) & 1;

    KF kfa, kfb;
#pragma unroll
    for (int js = 0; js < 4; js++) {
        const unsigned short* kp = keh + (size_t)phase * 4096 + (size_t)js * 1024 + l8;
        kfa.lo[js] = *(const short8*)kp;
        kfa.hi[js] = *(const short8*)(kp + 512);
    }

    auto step = [&](int s, KF& cur, KF& nxt) {
        int j0 = s * 64;
        bool doA = (s < itA);
        bool maskA = (s == itA - 1);
        bool maskB = (s == itB - 1);
        // prefetch K tile for this wave's NEXT step (s+2; overread past last tile
        // lands in the adjacent ke/vt region: harmless, allocated ws)
        {
            const unsigned short* kb = keh + (size_t)(s + 2) * 4096 + l8;
#pragma unroll
            for (int js = 0; js < 4; js++) {
                nxt.lo[js] = *(const short8*)(kb + js * 1024);
                nxt.hi[js] = *(const short8*)(kb + js * 1024 + 512);
            }
        }
        // V fragments for this tile (issued early to overlap the VALU chain)
        short8 vfr[2][4];
#pragma unroll
        for (int c = 0; c < 2; c++)
#pragma unroll
            for (int dt = 0; dt < 4; dt++)
                vfr[c][dt] = *(const short8*)(vth + (size_t)((j0 >> 5) + c) * 2048 + dt * 512 + l8);
        // bias: issue loads now, consume after the MFMAs
        float bv[4][4];
#pragma unroll
        for (int js = 0; js < 4; js++) {
            float4 bj = *(const float4*)&biash[j0 + js * 16 + lq * 4];
            bv[js][0] = bj.x; bv[js][1] = bj.y; bv[js][2] = bj.z; bv[js][3] = bj.w;
        }
        // QK MFMAs, zero C-init (B always, A if live)
        floatx4 sb4[4], sa4[4];
#pragma unroll
        for (int js = 0; js < 4; js++) {
            floatx4 sb = {0.f, 0.f, 0.f, 0.f};
            sb = __builtin_amdgcn_mfma_f32_16x16x32_bf16(cur.lo[js], qB0, sb, 0, 0, 0);
            sb = __builtin_amdgcn_mfma_f32_16x16x32_bf16(cur.hi[js], qB1, sb, 0, 0, 0);
            sb4[js] = sb;
        }
        if (doA) {
#pragma unroll
            for (int js = 0; js < 4; js++) {
                floatx4 sa = {0.f, 0.f, 0.f, 0.f};
                sa = __builtin_amdgcn_mfma_f32_16x16x32_bf16(cur.lo[js], qA0, sa, 0, 0, 0);
                sa = __builtin_amdgcn_mfma_f32_16x16x32_bf16(cur.hi[js], qA1, sa, 0, 0, 0);
                sa4[js] = sa;
            }
        }
        // stream B: add bias, mask diagonal, exp
        float svB[4][4];
#pragma unroll
        for (int js = 0; js < 4; js++)
#pragma unroll
            for (int r = 0; r < 4; r++) svB[js][r] = sb4[js][r] + bv[js][r];
        if (maskB) {
#pragma unroll
            for (int js = 0; js < 4; js++) {
                int jb = j0 + js * 16 + lq * 4;
#pragma unroll
                for (int r = 0; r < 4; r++)
                    if (jb + r > irowB) svB[js][r] = -1e9f;   // exp2 -> 0
            }
        }
        unsigned int pkB[4][2];
        exp_pack(svB, lB, pkB);

        if (doA) {
            float svA[4][4];
#pragma unroll
            for (int js = 0; js < 4; js++)
#pragma unroll
                for (int r = 0; r < 4; r++) svA[js][r] = sa4[js][r] + bv[js][r];
            if (maskA) {
#pragma unroll
                for (int js = 0; js < 4; js++) {
                    int jb = j0 + js * 16 + lq * 4;
#pragma unroll
                    for (int r = 0; r < 4; r++)
                        if (jb + r > irowA) svA[js][r] = -1e9f;
                }
            }
            unsigned int pkA[4][2];
            exp_pack(svA, lA, pkA);
#pragma unroll
            for (int c = 0; c < 2; c++) {
                short8 pfA = make_pf(pkA, c, srcLo, srcHi, hi);
                short8 pfB = make_pf(pkB, c, srcLo, srcHi, hi);
#pragma unroll
                for (int dt = 0; dt < 4; dt++) {
                    OA[dt] = __builtin_amdgcn_mfma_f32_16x16x32_bf16(vfr[c][dt], pfA, OA[dt], 0, 0, 0);
                    OB[dt] = __builtin_amdgcn_mfma_f32_16x16x32_bf16(vfr[c][dt], pfB, OB[dt], 0, 0, 0);
                }
            }
        } else {
#pragma unroll
            for (int c = 0; c < 2; c++) {
                short8 pfB = make_pf(pkB, c, srcLo, srcHi, hi);
#pragma unroll
                for (int dt = 0; dt < 4; dt++)
                    OB[dt] = __builtin_amdgcn_mfma_f32_16x16x32_bf16(vfr[c][dt], pfB, OB[dt], 0, 0, 0);
            }
        }
    };

    // stride-2 step loop: this wave owns steps s = phase, phase+2, ...
    int s = phase;
    for (; s + 2 < itB; s += 4) {        // ping-pong: no register-swap movs
        step(s, kfa, kfb);
        step(s + 2, kfb, kfa);
    }
    if (s < itB) step(s, kfa, kfb);

    // combine phase partials through LDS (max-free softmax => purely additive)
    if (phase == 1) {
        float* dst = psum[pairL][l];
#pragma unroll
        for (int dt = 0; dt < 4; dt++) *(floatx4*)&dst[dt * 4] = OA[dt];
#pragma unroll
        for (int dt = 0; dt < 4; dt++) *(floatx4*)&dst[16 + dt * 4] = OB[dt];
        dst[32] = lA; dst[33] = lB;
    }
    __syncthreads();
    if (phase == 1) return;
    {
        const float* src = psum[pairL][l];
#pragma unroll
        for (int dt = 0; dt < 4; dt++) {
            OA[dt] += *(const floatx4*)&src[dt * 4];
            OB[dt] += *(const floatx4*)&src[16 + dt * 4];
        }
        lA += src[32]; lB += src[33];
    }

    // epilogue: reduce the per-lane partial denominators across quads, then write
    lA += __shfl_xor(lA, 16); lA += __shfl_xor(lA, 32);
    lB += __shfl_xor(lB, 16); lB += __shfl_xor(lB, 32);
    {
        float inv = 1.0f / lA;
        unsigned short* orow = obf + (size_t)(b * T_ + irowA) * C_ + h * 64;
#pragma unroll
        for (int dt = 0; dt < 4; dt++) {
            union { unsigned short u[4]; short4v s4; } o;
#pragma unroll
            for (int r = 0; r < 4; r++) o.u[r] = f2bf(OA[dt][r] * inv);
            *(short4v*)&orow[dt * 16 + lq * 4] = o.s4;
        }
    }
    {
        float inv = 1.0f / lB;
        unsigned short* orow = obf + (size_t)(b * T_ + irowB) * C_ + h * 64;
#pragma unroll
        for (int dt = 0; dt < 4; dt++) {
            union { unsigned short u[4]; short4v s4; } o;
#pragma unroll
            for (int r = 0; r < 4; r++) o.u[r] = f2bf(OB[dt][r] * inv);
            *(short4v*)&orow[dt * 16 + lq * 4] = o.s4;
        }
    }
}

extern "C" void kernel_launch(void* const* d_in, const int* in_sizes, int n_in,
                              void* d_out, int out_size, void* d_ws, size_t ws_size,
                              hipStream_t stream) {
    const float* x       = (const float*)d_in[0];
    const float* W_attn  = (const float*)d_in[1];
    const float* W_proj  = (const float*)d_in[2];
    const float* W_recip = (const float*)d_in[3];
    const float* w_std   = (const float*)d_in[4];
    const float* w_rec   = (const float*)d_in[5];
    const float* w_disc  = (const float*)d_in[6];
    const float* d_bias  = (const float*)d_in[7];

    char* ws = (char*)d_ws;
    size_t o = 0;
    unsigned short* x_bf = (unsigned short*)(ws + o); o += (size_t)4096 * 1024 * 2;
    unsigned short* wa_t = (unsigned short*)(ws + o); o += (size_t)3072 * 1024 * 2;
    unsigned short* wp_t = (unsigned short*)(ws + o); o += (size_t)1024 * 1024 * 2;
    unsigned short* qe   = (unsigned short*)(ws + o); o += (size_t)32 * 2048 * 64 * 2;
    unsigned short* ke   = (unsigned short*)(ws + o); o += (size_t)32 * 2048 * 64 * 2;  // k_attn may overread ~16KB into vt: harmless
    unsigned short* vt   = (unsigned short*)(ws + o); o += (size_t)32 * 2048 * 64 * 2;
    unsigned short* obf  = (unsigned short*)(ws + o); o += (size_t)4096 * 1024 * 2;
    float* bias          = (float*)(ws + o);          o += (size_t)16 * 2048 * 4;

    k_prep<<<2848, 256, 0, stream>>>(x, W_attn, W_recip, w_std, w_rec, x_bf, wa_t);
    k_gemm_qkv<<<1040, 256, 0, stream>>>(x_bf, wa_t, W_proj, d_bias, w_disc,
                                         qe, ke, vt, wp_t, bias, 4096, 3072, 1024);
    k_attn<<<dim3(32, 32), 256, 0, stream>>>(qe, ke, vt, bias, obf);
    k_gemm64<<<dim3(16, 32), 256, 0, stream>>>(obf, wp_t, (float*)d_out, 4096, 1024, 1024);
}

// Round 15
// 191.018 us; speedup vs baseline: 1.0120x; 1.0120x over previous
//
#include <hip/hip_runtime.h>
#include <hip/hip_bf16.h>

#define DEVI __device__ __forceinline__

typedef __attribute__((ext_vector_type(8))) short short8;
typedef __attribute__((ext_vector_type(4))) short short4v;
typedef __attribute__((ext_vector_type(4))) float floatx4;

static constexpr int B_ = 2, T_ = 2048, C_ = 1024, H_ = 16, D_ = 64;
static constexpr float LOG2E = 1.44269504088896f;

DEVI float bf2f(unsigned short u) {
    union { unsigned int i; float f; } v; v.i = ((unsigned int)u) << 16; return v.f;
}
DEVI unsigned short f2bf(float f) {
    union { float f; unsigned int i; } v; v.f = f;
    unsigned int x = v.i;
    return (unsigned short)((x + 0x7fffu + ((x >> 16) & 1u)) >> 16);
}
DEVI unsigned int pk2bf(float lo, float hi) {
#if __has_builtin(__builtin_amdgcn_cvt_pk_bf16_f32)
    typedef __attribute__((ext_vector_type(2))) __bf16 bf16x2;
    union { bf16x2 v; unsigned int u; } r;
    r.v = __builtin_amdgcn_cvt_pk_bf16_f32(lo, hi);
    return r.u;
#else
    return (unsigned int)f2bf(lo) | ((unsigned int)f2bf(hi) << 16);
#endif
}
DEVI float fast_exp2(float x) {
#if __has_builtin(__builtin_amdgcn_exp2f)
    return __builtin_amdgcn_exp2f(x);
#else
    return __expf(x * 0.6931471805599453f);
#endif
}

// async global->LDS, 16B per lane. LDS dest must be wave_base + lane*16.
DEVI void async16(const unsigned short* g, unsigned short* l) {
    __builtin_amdgcn_global_load_lds((const __attribute__((address_space(1))) void*)g,
                                     (__attribute__((address_space(3))) void*)l, 16, 0, 0);
}

// ================= shared prep bodies =================
DEVI void tr_body(const float* in, unsigned short* out, int K, int N, int bx, int by,
                  int tid, float (*tile)[65], float scale, bool skiphi) {
    int k0 = by * 64, n0 = bx * 64;
#pragma unroll
    for (int r = 0; r < 4; r++) {
        int ci = tid + r * 256;
        int row = ci >> 4, c4 = (ci & 15) * 4;
        float4 v = *(const float4*)&in[(size_t)(k0 + row) * N + n0 + c4];
        tile[row][c4 + 0] = v.x; tile[row][c4 + 1] = v.y;
        tile[row][c4 + 2] = v.z; tile[row][c4 + 3] = v.w;
    }
    __syncthreads();
#pragma unroll
    for (int r = 0; r < 2; r++) {
        int ci = tid + r * 256;
        int row = ci >> 3, c8 = (ci & 7) * 8;
        if (skiphi && row >= 56) continue;   // aug blocks own these output rows
        union { unsigned short u[8]; short8 s; } o;
#pragma unroll
        for (int j = 0; j < 8; j++) o.u[j] = f2bf(tile[c8 + j][row] * scale);
        *(short8*)&out[(size_t)(n0 + row) * K + k0 + c8] = o.s;
    }
}

DEVI void bias_body(const float* d_bias, const float* w_disc, float* bias,
                    int h, int tid, float* red) {
    float s = 0.f;
    for (int t = tid; t < T_; t += 256) s += d_bias[h * T_ + t];
    red[tid] = s;
    __syncthreads();
    for (int st = 128; st > 0; st >>= 1) {
        if (tid < st) red[tid] += red[tid + st];
        __syncthreads();
    }
    float mean = red[0] * (1.0f / T_);
    float wd = w_disc[h] * LOG2E;
    for (int t = tid; t < T_; t += 256) bias[h * T_ + t] = (d_bias[h * T_ + t] - mean) * wd;
}

// ================= prep: x->bf16, W_attn^T (scaled/augmented) =================
// q_eff/k_eff are LINEAR in x, so the augmentation folds into the weights:
//   Wq_eff = [qscale*ws*Wq[:, :56], qscale*wr*(Wk@W_recip)]   (plain qscale*ws*Wq if !ra)
//   Wk_eff = [ws*Wk[:, :56],        wr*(Wq@W_recip)]          (plain ws*Wk if !ra)
// tr blocks skip q/k rows d>=56; aug blocks (32) write exactly those rows -> no race.
// wp_t + bias blocks live in the k_gemm_qkv launch (fill its idle CU slots).
__global__ __launch_bounds__(256) void k_prep(const float* __restrict__ x,
                                              const float* __restrict__ W_attn,
                                              const float* __restrict__ W_recip,
                                              const float* __restrict__ w_std,
                                              const float* __restrict__ w_rec,
                                              unsigned short* __restrict__ x_bf,
                                              unsigned short* __restrict__ wa_t) {
    __shared__ float tile[64][65];
    int bid = blockIdx.x, tid = threadIdx.x;
    if (bid < 2048) {
        int i = bid * 256 + tid;
        const float4* p = (const float4*)x + (size_t)i * 2;
        float4 a = p[0], b = p[1];
        union { unsigned short u[8]; short8 s; } r;
        r.u[0] = f2bf(a.x); r.u[1] = f2bf(a.y); r.u[2] = f2bf(a.z); r.u[3] = f2bf(a.w);
        r.u[4] = f2bf(b.x); r.u[5] = f2bf(b.y); r.u[6] = f2bf(b.z); r.u[7] = f2bf(b.w);
        *(short8*)&x_bf[(size_t)i * 8] = r.s;
    } else if (bid < 2816) {
        int idx = bid - 2048;
        int bx = idx % 48, by = idx / 48;
        int sec = bx >> 4, h = bx & 15;
        float ws = sqrtf(fmaxf(w_std[h], 1e-8f));
        float sc = (sec == 0) ? ws * (0.125f * LOG2E) : (sec == 1 ? ws : 1.0f);
        tr_body(W_attn, wa_t, 1024, 3072, bx, by, tid, tile, sc, sec < 2);
    } else {
        // augmented weight rows: for (h, side) write wa_t rows side*1024 + h*64 + 56..63
        int idx = bid - 2816;           // 0..31
        int h = idx & 15, side = idx >> 4;   // side 0: q_eff rows, 1: k_eff rows
        float* WrS = &tile[0][0];
        for (int i = tid; i < 512; i += 256) WrS[i] = W_recip[i];
        __syncthreads();
        float wrv = sqrtf(fmaxf(w_rec[h], 1e-8f));
        float wsv = sqrtf(fmaxf(w_std[h], 1e-8f));
        bool ra = w_rec[h] > 0.1f;
        float sc = (side == 0 ? 0.125f * LOG2E : 1.0f) * (ra ? wrv : wsv);
        int dst0 = side * 1024 + h * 64 + 56;
        for (int kk = tid; kk < 1024; kk += 256) {
            const float* srow = W_attn + (size_t)kk * 3072;
            float out[8];
            if (ra) {
                // q_aug <- Wk@Wr, k_aug <- Wq@Wr (other side's columns)
                int sc0 = (1 - side) * 1024 + h * 64;
#pragma unroll
                for (int r = 0; r < 8; r++) out[r] = 0.f;
                for (int dd = 0; dd < 64; dd++) {
                    float v = srow[sc0 + dd];
#pragma unroll
                    for (int r = 0; r < 8; r++) out[r] += v * WrS[dd * 8 + r];
                }
            } else {
                int sc0 = side * 1024 + h * 64 + 56;   // plain same-side columns
#pragma unroll
                for (int r = 0; r < 8; r++) out[r] = srow[sc0 + r];
            }
#pragma unroll
            for (int r = 0; r < 8; r++)
                wa_t[(size_t)(dst0 + r) * 1024 + kk] = f2bf(sc * out[r]);
        }
    }
}

// ========== bf16 GEMM 128x128 -> fragment-linear qe/ke/vt (+ folded wp_t/bias) ==========
// R12: BK=64 dual 32-wide buffers (32 MFMAs per barrier pair); epilogue staging unions
// with k-loop buffers (LDS 32KB -> 4 blocks/CU). R10: XCD-locality 2D chunk.
// R13: 1D grid 1040 — blocks 0..767 GEMM, 768..1023 wp_t transpose, 1024..1039 bias.
// R15 (final): session-best configuration restored (192.4us). Further GEMM gains need
// the 8-phase counted-vmcnt 256^2 template — a new sync structure that cannot be
// race-screened in this loop (non-attn dispatches invisible in top-5 counters).
__global__ __launch_bounds__(256) void k_gemm_qkv(const unsigned short* __restrict__ A,
                                                  const unsigned short* __restrict__ Bt,
                                                  const float* __restrict__ W_proj,
                                                  const float* __restrict__ d_bias,
                                                  const float* __restrict__ w_disc,
                                                  unsigned short* __restrict__ qe,
                                                  unsigned short* __restrict__ ke,
                                                  unsigned short* __restrict__ vt,
                                                  unsigned short* __restrict__ wp_t,
                                                  float* __restrict__ bias,
                                                  int M, int N, int K) {
    union SM {
        unsigned short buf[4][128 * 32];    // A0,A1,B0,B1 (k-loop)        32 KB
        unsigned short stg[4][4096];        // per-wave staging (epilogue) 32 KB
        struct { float tile[64][65]; float red[256]; } p;   // prep blocks ~17.7 KB
    };
    __shared__ __align__(16) SM sm;
    int bid = blockIdx.x, tid = threadIdx.x;
    if (bid >= 768) {
        if (bid < 1024) {
            int idx = bid - 768;
            tr_body(W_proj, wp_t, 1024, 1024, idx & 15, idx >> 4, tid, sm.p.tile, 1.0f, false);
        } else {
            bias_body(d_bias, w_disc, bias, bid - 1024, tid, sm.p.red);
        }
        return;
    }
    int b1d = bid;                              // HW linear id
    int xcd = b1d & 7, i6 = b1d >> 3;           // i6: 0..95
    int bx = (xcd & 1) * 12 + i6 % 12;          // 2 bx-groups x 4 by-groups = 8 XCD tiles
    int by = (xcd >> 1) * 8 + i6 / 12;
    int m0 = by * 128, n0 = bx * 128;
    int l = tid & 63, w = tid >> 6;
    int wm = (w >> 1) * 64, wn = (w & 1) * 64;
    int lm = l & 15, lq = l >> 4;
    floatx4 acc[4][4];
#pragma unroll
    for (int a = 0; a < 4; a++)
#pragma unroll
        for (int b = 0; b < 4; b++) acc[a][b] = {0.f, 0.f, 0.f, 0.f};

    for (int k0 = 0; k0 < K; k0 += 64) {
        __syncthreads();
#pragma unroll
        for (int r = 0; r < 2; r++) {
            int ci = tid + r * 256;
            int row = ci >> 2, off = (ci & 3) * 8;
            async16(&A[(size_t)(m0 + row) * K + k0 + off],       &sm.buf[0][row * 32 + off]);
            async16(&A[(size_t)(m0 + row) * K + k0 + 32 + off],  &sm.buf[1][row * 32 + off]);
            async16(&Bt[(size_t)(n0 + row) * K + k0 + off],      &sm.buf[2][row * 32 + off]);
            async16(&Bt[(size_t)(n0 + row) * K + k0 + 32 + off], &sm.buf[3][row * 32 + off]);
        }
        __syncthreads();
#pragma unroll
        for (int half = 0; half < 2; half++) {
            const unsigned short* Ah = sm.buf[half];
            const unsigned short* Bh = sm.buf[2 + half];
            short8 af[4], bf[4];
#pragma unroll
            for (int t = 0; t < 4; t++) af[t] = *(short8*)&Ah[(wm + t * 16 + lm) * 32 + lq * 8];
#pragma unroll
            for (int t = 0; t < 4; t++) bf[t] = *(short8*)&Bh[(wn + t * 16 + lm) * 32 + lq * 8];
#pragma unroll
            for (int tm = 0; tm < 4; tm++)
#pragma unroll
                for (int tn = 0; tn < 4; tn++)
                    acc[tm][tn] = __builtin_amdgcn_mfma_f32_16x16x32_bf16(af[tm], bf[tn], acc[tm][tn], 0, 0, 0);
        }
    }
    __syncthreads();    // all waves done reading buf before stg overwrites it
    // ---- epilogue: stage fragment-linear tile in LDS, then coalesced copy-out ----
    int sec = bx >> 3;                      // 0=q_eff, 1=k_eff, 2=v  (block-uniform)
    int b = by >> 4;                        // batch
    int head = ((n0 & 1023) >> 6) + (wn >> 6);
    size_t bhbase = (size_t)(b * 16 + head) * 131072;
    int tloc0 = (m0 & 2047) + wm;           // wave's first t within batch (multiple of 64)
    unsigned short* dst = (sec == 0) ? qe : (sec == 1) ? ke : vt;
    unsigned short* S = sm.stg[w];
    if (sec < 2) {
        // qe/ke elem(t,d): (t>>4)*1024 + (t&15)*8 + (d>>5)*512 + ((d>>3)&3)*128 + (d&7)
#pragma unroll
        for (int tm = 0; tm < 4; tm++)
#pragma unroll
            for (int tn = 0; tn < 4; tn++) {
                int base = tm * 1024 + (tn >> 1) * 512 + ((tn & 1) * 2 + (lm >> 3)) * 128 +
                           (lm & 7) + lq * 32;           // + r*8 per element
#pragma unroll
                for (int r = 0; r < 4; r++) S[base + r * 8] = f2bf(acc[tm][tn][r]);
            }
    } else {
        // vt elem(t,d): (t>>5)*2048 + (d>>4)*512 + ((t>>3)&3)*128 + (d&15)*8 + (t&7)
#pragma unroll
        for (int tm = 0; tm < 4; tm++)
#pragma unroll
            for (int tn = 0; tn < 4; tn++) {
                int base = (tm >> 1) * 2048 + tn * 512 + ((tm & 1) * 2 + (lq >> 1)) * 128 +
                           lm * 8 + (lq & 1) * 4;        // r contiguous
                union { unsigned short u[4]; short4v s4; } o;
#pragma unroll
                for (int r = 0; r < 4; r++) o.u[r] = f2bf(acc[tm][tn][r]);
                *(short4v*)&S[base] = o.s4;
            }
    }
    // same-wave LDS RAW: compiler inserts the lgkmcnt wait; no cross-wave sharing.
    size_t gbase = bhbase + ((sec < 2) ? (size_t)(tloc0 >> 4) * 1024
                                       : (size_t)(tloc0 >> 5) * 2048);
#pragma unroll
    for (int i = 0; i < 8; i++) {
        short8 v = *(const short8*)&S[(size_t)(i * 64 + l) * 8];
        *(short8*)&dst[gbase + (size_t)(i * 64 + l) * 8] = v;
    }
}

// ================= bf16 GEMM 128x64 (fp32 out) — for the proj GEMM =================
// NOTE (R4): keep 128x64 / 512-block shape for N=1024 (2 blocks/CU).
// R13/R15: BK=128 via 4 sub-buffers (48KB LDS; grid-capped at 2 blocks/CU so no
// occupancy cost) — the session-best configuration (R13 192.4 vs R14 BK=64 193.3).
// R10: XCD-locality 8x8 chunk.
__global__ __launch_bounds__(256) void k_gemm64(const unsigned short* __restrict__ A,
                                                const unsigned short* __restrict__ Bt,
                                                float* __restrict__ C, int M, int N, int K) {
    __shared__ __align__(16) unsigned short As[4][128 * 32];
    __shared__ __align__(16) unsigned short Bs[4][64 * 32];
    int b1d = blockIdx.y * 16 + blockIdx.x;     // HW linear id (x fastest)
    int xcd = b1d & 7, i6 = b1d >> 3;           // i6: 0..63
    int bx = (xcd & 1) * 8 + (i6 & 7);          // 2 bx-groups x 4 by-groups = 8 XCD tiles
    int by = (xcd >> 1) * 8 + (i6 >> 3);
    int m0 = by * 128, n0 = bx * 64;
    int tid = threadIdx.x, l = tid & 63, w = tid >> 6;
    int wm = w * 32;
    int lm = l & 15, lq = l >> 4;
    floatx4 acc[2][4];
#pragma unroll
    for (int a = 0; a < 2; a++)
#pragma unroll
        for (int b = 0; b < 4; b++) acc[a][b] = {0.f, 0.f, 0.f, 0.f};

    for (int k0 = 0; k0 < K; k0 += 128) {
        __syncthreads();
#pragma unroll
        for (int r = 0; r < 2; r++) {
            int ci = tid + r * 256;
            int row = ci >> 2, off = (ci & 3) * 8;
#pragma unroll
            for (int q = 0; q < 4; q++)
                async16(&A[(size_t)(m0 + row) * K + k0 + q * 32 + off], &As[q][row * 32 + off]);
        }
        {
            int row = tid >> 2, off = (tid & 3) * 8;
#pragma unroll
            for (int q = 0; q < 4; q++)
                async16(&Bt[(size_t)(n0 + row) * K + k0 + q * 32 + off], &Bs[q][row * 32 + off]);
        }
        __syncthreads();
#pragma unroll
        for (int q = 0; q < 4; q++) {
            short8 af[2], bf[4];
#pragma unroll
            for (int t = 0; t < 2; t++) af[t] = *(short8*)&As[q][(wm + t * 16 + lm) * 32 + lq * 8];
#pragma unroll
            for (int t = 0; t < 4; t++) bf[t] = *(short8*)&Bs[q][(t * 16 + lm) * 32 + lq * 8];
#pragma unroll
            for (int tm = 0; tm < 2; tm++)
#pragma unroll
                for (int tn = 0; tn < 4; tn++)
                    acc[tm][tn] = __builtin_amdgcn_mfma_f32_16x16x32_bf16(af[tm], bf[tn], acc[tm][tn], 0, 0, 0);
        }
    }
#pragma unroll
    for (int tm = 0; tm < 2; tm++)
#pragma unroll
        for (int tn = 0; tn < 4; tn++) {
            int row = m0 + wm + tm * 16 + lq * 4;
            int col = n0 + tn * 16 + lm;
#pragma unroll
            for (int r = 0; r < 4; r++) C[(size_t)(row + r) * N + col] = acc[tm][tn][r];
        }
}

// ================= attention helpers =================
// Max-free softmax: scores in log2 domain are tiny (|s| < ~10 << 128), so
// exp2 cannot overflow and the running max / alpha rescale is unnecessary.
// l is a per-lane partial, reduced once in the epilogue.
DEVI void exp_pack(float sv[4][4], float& l_part, unsigned int pk[4][2]) {
#pragma unroll
    for (int js = 0; js < 4; js++)
#pragma unroll
        for (int r = 0; r < 4; r++) {
            float p = fast_exp2(sv[js][r]);
            sv[js][r] = p;
            l_part += p;
        }
#pragma unroll
    for (int js = 0; js < 4; js++) {
        pk[js][0] = pk2bf(sv[js][0], sv[js][1]);
        pk[js][1] = pk2bf(sv[js][2], sv[js][3]);
    }
}

DEVI short8 make_pf(const unsigned int pk[4][2], int c, int srcLo, int srcHi, bool hi) {
    int a0 = __shfl((int)pk[2 * c][0], srcLo);
    int a1 = __shfl((int)pk[2 * c][1], srcLo);
    int a2 = __shfl((int)pk[2 * c][0], srcHi);
    int a3 = __shfl((int)pk[2 * c][1], srcHi);
    int b0 = __shfl((int)pk[2 * c + 1][0], srcLo);
    int b1 = __shfl((int)pk[2 * c + 1][1], srcLo);
    int b2 = __shfl((int)pk[2 * c + 1][0], srcHi);
    int b3 = __shfl((int)pk[2 * c + 1][1], srcHi);
    union { int i[4]; short8 s; } pf;
    pf.i[0] = hi ? b0 : a0;
    pf.i[1] = hi ? b1 : a1;
    pf.i[2] = hi ? b2 : a2;
    pf.i[3] = hi ? b3 : a3;
    return pf.s;
}

struct KF { short8 lo[4]; short8 hi[4]; };

// ================= flash attention: paired tiles + phase-split + XCD swizzle ===========
// R9: XCD swizzle -> K/V L2-resident (FETCH 63.5->12.5MB). R11: phase-split in the
// latency-bound regime -> 50.4->49.2us. Structural floor for this decomposition
// (7 variants tested, 49-59us; occupancy at the 128-VGPR cap).
__global__ __launch_bounds__(256) void k_attn(const unsigned short* __restrict__ qe,
                                              const unsigned short* __restrict__ ke,
                                              const unsigned short* __restrict__ vt,
                                              const float* __restrict__ bias,
                                              unsigned short* __restrict__ obf) {
    __shared__ __align__(16) float psum[2][64][36];   // [pairL][lane][OA16|OB16|lA|lB]
    int b1d = blockIdx.y * 32 + blockIdx.x;     // HW linear id (x fastest)
    int xcd = b1d & 7, j = b1d >> 3;            // j: 0..127
    int bh = xcd * 4 + (j >> 5);                // 4 bh per XCD (L2-resident K/V)
    int pxq = j & 31;                           // pair-quad within bh: 0..31
    int b = bh >> 4, h = bh & 15;
    int tid = threadIdx.x, l = tid & 63, w = tid >> 6;
    int pairL = w >> 1;                         // local pair: 0/1
    int phase = w & 1;                          // 0: even steps, 1: odd steps
    int lm = l & 15, lq = l >> 4;
    int l8 = l * 8;
    const size_t hb = (size_t)bh * 131072;
    const unsigned short* qeh = qe + hb;
    const unsigned short* keh = ke + hb;
    const unsigned short* vth = vt + hb;
    const float* biash = bias + h * T_;

    int gA = pxq * 2 + pairL;               // 0..63 (light tile)
    int gB = 127 - gA;                      // 64..127 (heavy tile)
    int itA = (gA >> 2) + 1, itB = (gB >> 2) + 1;
    int irowA = gA * 16 + lm, irowB = gB * 16 + lm;

    short8 qA0 = *(const short8*)(qeh + (size_t)gA * 1024 + l8);
    short8 qA1 = *(const short8*)(qeh + (size_t)gA * 1024 + 512 + l8);
    short8 qB0 = *(const short8*)(qeh + (size_t)gB * 1024 + l8);
    short8 qB1 = *(const short8*)(qeh + (size_t)gB * 1024 + 512 + l8);

    floatx4 OA[4], OB[4];
#pragma unroll
    for (int i = 0; i < 4; i++) { OA[i] = {0.f, 0.f, 0.f, 0.f}; OB[i] = {0.f, 0.f, 0.f, 0.f}; }
    float lA = 0.f, lB = 0.f;               // per-lane partial denominators

    const int srcLo = ((lq & 1) * 2) * 16 + lm;
    const int srcHi = srcLo + 16;
    const bool hi = (lq >> 1) & 1;

    KF kfa, kfb;
#pragma unroll
    for (int js = 0; js < 4; js++) {
        const unsigned short* kp = keh + (size_t)phase * 4096 + (size_t)js * 1024 + l8;
        kfa.lo[js] = *(const short8*)kp;
        kfa.hi[js] = *(const short8*)(kp + 512);
    }

    auto step = [&](int s, KF& cur, KF& nxt) {
        int j0 = s * 64;
        bool doA = (s < itA);
        bool maskA = (s == itA - 1);
        bool maskB = (s == itB - 1);
        // prefetch K tile for this wave's NEXT step (s+2; overread past last tile
        // lands in the adjacent ke/vt region: harmless, allocated ws)
        {
            const unsigned short* kb = keh + (size_t)(s + 2) * 4096 + l8;
#pragma unroll
            for (int js = 0; js < 4; js++) {
                nxt.lo[js] = *(const short8*)(kb + js * 1024);
                nxt.hi[js] = *(const short8*)(kb + js * 1024 + 512);
            }
        }
        // V fragments for this tile (issued early to overlap the VALU chain)
        short8 vfr[2][4];
#pragma unroll
        for (int c = 0; c < 2; c++)
#pragma unroll
            for (int dt = 0; dt < 4; dt++)
                vfr[c][dt] = *(const short8*)(vth + (size_t)((j0 >> 5) + c) * 2048 + dt * 512 + l8);
        // bias: issue loads now, consume after the MFMAs
        float bv[4][4];
#pragma unroll
        for (int js = 0; js < 4; js++) {
            float4 bj = *(const float4*)&biash[j0 + js * 16 + lq * 4];
            bv[js][0] = bj.x; bv[js][1] = bj.y; bv[js][2] = bj.z; bv[js][3] = bj.w;
        }
        // QK MFMAs, zero C-init (B always, A if live)
        floatx4 sb4[4], sa4[4];
#pragma unroll
        for (int js = 0; js < 4; js++) {
            floatx4 sb = {0.f, 0.f, 0.f, 0.f};
            sb = __builtin_amdgcn_mfma_f32_16x16x32_bf16(cur.lo[js], qB0, sb, 0, 0, 0);
            sb = __builtin_amdgcn_mfma_f32_16x16x32_bf16(cur.hi[js], qB1, sb, 0, 0, 0);
            sb4[js] = sb;
        }
        if (doA) {
#pragma unroll
            for (int js = 0; js < 4; js++) {
                floatx4 sa = {0.f, 0.f, 0.f, 0.f};
                sa = __builtin_amdgcn_mfma_f32_16x16x32_bf16(cur.lo[js], qA0, sa, 0, 0, 0);
                sa = __builtin_amdgcn_mfma_f32_16x16x32_bf16(cur.hi[js], qA1, sa, 0, 0, 0);
                sa4[js] = sa;
            }
        }
        // stream B: add bias, mask diagonal, exp
        float svB[4][4];
#pragma unroll
        for (int js = 0; js < 4; js++)
#pragma unroll
            for (int r = 0; r < 4; r++) svB[js][r] = sb4[js][r] + bv[js][r];
        if (maskB) {
#pragma unroll
            for (int js = 0; js < 4; js++) {
                int jb = j0 + js * 16 + lq * 4;
#pragma unroll
                for (int r = 0; r < 4; r++)
                    if (jb + r > irowB) svB[js][r] = -1e9f;   // exp2 -> 0
            }
        }
        unsigned int pkB[4][2];
        exp_pack(svB, lB, pkB);

        if (doA) {
            float svA[4][4];
#pragma unroll
            for (int js = 0; js < 4; js++)
#pragma unroll
                for (int r = 0; r < 4; r++) svA[js][r] = sa4[js][r] + bv[js][r];
            if (maskA) {
#pragma unroll
                for (int js = 0; js < 4; js++) {
                    int jb = j0 + js * 16 + lq * 4;
#pragma unroll
                    for (int r = 0; r < 4; r++)
                        if (jb + r > irowA) svA[js][r] = -1e9f;
                }
            }
            unsigned int pkA[4][2];
            exp_pack(svA, lA, pkA);
#pragma unroll
            for (int c = 0; c < 2; c++) {
                short8 pfA = make_pf(pkA, c, srcLo, srcHi, hi);
                short8 pfB = make_pf(pkB, c, srcLo, srcHi, hi);
#pragma unroll
                for (int dt = 0; dt < 4; dt++) {
                    OA[dt] = __builtin_amdgcn_mfma_f32_16x16x32_bf16(vfr[c][dt], pfA, OA[dt], 0, 0, 0);
                    OB[dt] = __builtin_amdgcn_mfma_f32_16x16x32_bf16(vfr[c][dt], pfB, OB[dt], 0, 0, 0);
                }
            }
        } else {
#pragma unroll
            for (int c = 0; c < 2; c++) {
                short8 pfB = make_pf(pkB, c, srcLo, srcHi, hi);
#pragma unroll
                for (int dt = 0; dt < 4; dt++)
                    OB[dt] = __builtin_amdgcn_mfma_f32_16x16x32_bf16(vfr[c][dt], pfB, OB[dt], 0, 0, 0);
            }
        }
    };

    // stride-2 step loop: this wave owns steps s = phase, phase+2, ...
    int s = phase;
    for (; s + 2 < itB; s += 4) {        // ping-pong: no register-swap movs
        step(s, kfa, kfb);
        step(s + 2, kfb, kfa);
    }
    if (s < itB) step(s, kfa, kfb);

    // combine phase partials through LDS (max-free softmax => purely additive)
    if (phase == 1) {
        float* dst = psum[pairL][l];
#pragma unroll
        for (int dt = 0; dt < 4; dt++) *(floatx4*)&dst[dt * 4] = OA[dt];
#pragma unroll
        for (int dt = 0; dt < 4; dt++) *(floatx4*)&dst[16 + dt * 4] = OB[dt];
        dst[32] = lA; dst[33] = lB;
    }
    __syncthreads();
    if (phase == 1) return;
    {
        const float* src = psum[pairL][l];
#pragma unroll
        for (int dt = 0; dt < 4; dt++) {
            OA[dt] += *(const floatx4*)&src[dt * 4];
            OB[dt] += *(const floatx4*)&src[16 + dt * 4];
        }
        lA += src[32]; lB += src[33];
    }

    // epilogue: reduce the per-lane partial denominators across quads, then write
    lA += __shfl_xor(lA, 16); lA += __shfl_xor(lA, 32);
    lB += __shfl_xor(lB, 16); lB += __shfl_xor(lB, 32);
    {
        float inv = 1.0f / lA;
        unsigned short* orow = obf + (size_t)(b * T_ + irowA) * C_ + h * 64;
#pragma unroll
        for (int dt = 0; dt < 4; dt++) {
            union { unsigned short u[4]; short4v s4; } o;
#pragma unroll
            for (int r = 0; r < 4; r++) o.u[r] = f2bf(OA[dt][r] * inv);
            *(short4v*)&orow[dt * 16 + lq * 4] = o.s4;
        }
    }
    {
        float inv = 1.0f / lB;
        unsigned short* orow = obf + (size_t)(b * T_ + irowB) * C_ + h * 64;
#pragma unroll
        for (int dt = 0; dt < 4; dt++) {
            union { unsigned short u[4]; short4v s4; } o;
#pragma unroll
            for (int r = 0; r < 4; r++) o.u[r] = f2bf(OB[dt][r] * inv);
            *(short4v*)&orow[dt * 16 + lq * 4] = o.s4;
        }
    }
}

extern "C" void kernel_launch(void* const* d_in, const int* in_sizes, int n_in,
                              void* d_out, int out_size, void* d_ws, size_t ws_size,
                              hipStream_t stream) {
    const float* x       = (const float*)d_in[0];
    const float* W_attn  = (const float*)d_in[1];
    const float* W_proj  = (const float*)d_in[2];
    const float* W_recip = (const float*)d_in[3];
    const float* w_std   = (const float*)d_in[4];
    const float* w_rec   = (const float*)d_in[5];
    const float* w_disc  = (const float*)d_in[6];
    const float* d_bias  = (const float*)d_in[7];

    char* ws = (char*)d_ws;
    size_t o = 0;
    unsigned short* x_bf = (unsigned short*)(ws + o); o += (size_t)4096 * 1024 * 2;
    unsigned short* wa_t = (unsigned short*)(ws + o); o += (size_t)3072 * 1024 * 2;
    unsigned short* wp_t = (unsigned short*)(ws + o); o += (size_t)1024 * 1024 * 2;
    unsigned short* qe   = (unsigned short*)(ws + o); o += (size_t)32 * 2048 * 64 * 2;
    unsigned short* ke   = (unsigned short*)(ws + o); o += (size_t)32 * 2048 * 64 * 2;  // k_attn may overread ~16KB into vt: harmless
    unsigned short* vt   = (unsigned short*)(ws + o); o += (size_t)32 * 2048 * 64 * 2;
    unsigned short* obf  = (unsigned short*)(ws + o); o += (size_t)4096 * 1024 * 2;
    float* bias          = (float*)(ws + o);          o += (size_t)16 * 2048 * 4;

    k_prep<<<2848, 256, 0, stream>>>(x, W_attn, W_recip, w_std, w_rec, x_bf, wa_t);
    k_gemm_qkv<<<1040, 256, 0, stream>>>(x_bf, wa_t, W_proj, d_bias, w_disc,
                                         qe, ke, vt, wp_t, bias, 4096, 3072, 1024);
    k_attn<<<dim3(32, 32), 256, 0, stream>>>(qe, ke, vt, bias, obf);
    k_gemm64<<<dim3(16, 32), 256, 0, stream>>>(obf, wp_t, (float*)d_out, 4096, 1024, 1024);
}